// Round 24
// baseline (205.615 us; speedup 1.0000x reference)
//
#include <hip/hip_runtime.h>

#define SPLITK 256
#define FC1_K 55815
#define KP 55816  // padded bf16 row stride (16B-aligned rows)

__device__ __forceinline__ unsigned short f2bf(float f) {
    unsigned u = __float_as_uint(f);
    return (unsigned short)((u + 0x7FFFu + ((u >> 16) & 1u)) >> 16);  // RNE
}

// ============ conv1 + relu + pool1 fused (v11: conv2f-v5 shape — 15x15 tile, wave-private
// staging, 1 barrier, shfl+halo pool). Grid 10368 blocks (~5 residency rounds) for cross-block
// latency hiding; per-output FMA order (c->kh->kw) identical to v6 -> bitwise-same output.
__global__ __launch_bounds__(256) void conv1f_k(const float* __restrict__ in,
                                                const float* __restrict__ w,
                                                const float* __restrict__ bias,
                                                float* __restrict__ out) {
    __shared__ float smem[1872];  // 4 waves x 396 (11 rows x stride 36) + halo [3][6][16]=288
    const int tc = blockIdx.x, tr = blockIdx.y, b = blockIdx.z;
    const int pr0 = tr * 15, pc0 = tc * 15;
    const int tid = threadIdx.x;
    const int wv = tid >> 6, lane = tid & 63;
    const int ti = tid >> 4, tj = tid & 15;
    const int tl = ti & 3;
    float* wreg = smem + wv * 396;
    float* halo = smem + 1584;
    const float* inb = in + (size_t)b * 187500;
    const int irw = 2 * pr0 - 1 + 8 * wv;  // first input row of this wave's 11-row strip
    const int ic0 = 2 * pc0 - 1;
    const bool safe = (tr >= 1 && tr <= 7) && (tc >= 1 && tc <= 7);

    // hoisted stage offsets: 396 floats/wave, 6 full 64-lane iters + 1 masked (lane<12)
    int off[7];
    unsigned msk = 0u;
    {
        int y = lane / 36;
        int x = lane - y * 36;
        #pragma unroll
        for (int it = 0; it < 7; ++it) {
            int gr = irw + y, gc = ic0 + x;
            bool valid = ((unsigned)gr < 250u) && ((unsigned)gc < 250u) && (it < 6 || lane < 12);
            off[it] = valid ? (gr * 250 + gc) : 0;
            msk |= (valid ? 1u : 0u) << it;
            x += 28; ++y;                    // +64 == 36 + 28
            if (x >= 36) { x -= 36; ++y; }
        }
    }

    float acc[6];
    #pragma unroll
    for (int o = 0; o < 6; ++o) acc[o] = bias[o];

    for (int c = 0; c < 3; ++c) {
        const float* cp = inb + c * 62500;
        // wave-private stage: no barriers (wave-internal waitcnt orders LDS)
        if (safe) {
            #pragma unroll
            for (int it = 0; it < 6; ++it) wreg[lane + it * 64] = cp[off[it]];
            if (lane < 12) wreg[384 + lane] = cp[off[6]];
        } else {
            #pragma unroll
            for (int it = 0; it < 6; ++it) {
                float v = 0.0f;
                if ((msk >> it) & 1u) v = cp[off[it]];
                wreg[lane + it * 64] = v;
            }
            if (lane < 12) {
                float v = 0.0f;
                if ((msk >> 6) & 1u) v = cp[off[6]];
                wreg[384 + lane] = v;
            }
        }
        // compute: conv output (pr0+ti, pc0+tj); input rows 2tl+kh of this wave's strip
        #pragma unroll
        for (int kh = 0; kh < 5; ++kh) {
            const float* rp = &wreg[(2 * tl + kh) * 36 + 2 * tj];
            float r0, r1, r2, r3, r4;
            float4 v4 = *(const float4*)rp;
            r0 = v4.x; r1 = v4.y; r2 = v4.z; r3 = v4.w; r4 = rp[4];
            #pragma unroll
            for (int o = 0; o < 6; ++o) {
                const float* wr_ = &w[o * 75 + c * 25 + kh * 5];
                acc[o] = fmaf(r0, wr_[0], acc[o]);
                acc[o] = fmaf(r1, wr_[1], acc[o]);
                acc[o] = fmaf(r2, wr_[2], acc[o]);
                acc[o] = fmaf(r3, wr_[3], acc[o]);
                acc[o] = fmaf(r4, wr_[4], acc[o]);
            }
        }
    }

    // halo: waves 1..3 publish their first conv row (raw, pre-relu)
    if (tl == 0 && wv > 0) {
        #pragma unroll
        for (int o = 0; o < 6; ++o)
            halo[(wv - 1) * 96 + o * 16 + tj] = acc[o];
    }
    __syncthreads();  // the only barrier

    // pool 2x2 s1 via shfl (+halo at wave boundary), relu after max
    const int gr = pr0 + ti, gc = pc0 + tj;
    const bool valid = (ti < 15) && (tj < 15) && (gr < 123) && (gc < 123);
    const bool lastrow = (tl == 3);
    const int hb = (wv < 2 ? wv : 2) * 96;
    #pragma unroll
    for (int o = 0; o < 6; ++o) {
        float c00 = acc[o];
        float c01 = __shfl(acc[o], lane + 1);
        float s10 = __shfl(acc[o], lane + 16);
        float s11 = __shfl(acc[o], lane + 17);
        float h10 = halo[hb + o * 16 + tj];
        float h11 = halo[hb + o * 16 + (tj + 1 > 15 ? 15 : tj + 1)];
        float c10 = lastrow ? h10 : s10;
        float c11 = lastrow ? h11 : s11;
        float m = fmaxf(fmaxf(fmaxf(c00, c01), fmaxf(c10, c11)), 0.0f);
        if (valid) out[((size_t)(b * 6 + o) * 123 + gr) * 123 + gc] = m;
    }
}

// ============ conv2 + relu + pool2 fused (v5, r23-verbatim; writes bf16 D, padded rows) ============
__global__ __launch_bounds__(256) void conv2f_k(const float* __restrict__ in,
                                                const float* __restrict__ w,
                                                const float* __restrict__ bias,
                                                unsigned short* __restrict__ out) {
    __shared__ float smem[2000];
    const int tc = blockIdx.x, tr = blockIdx.y, b = blockIdx.z;
    const int pr0 = tr * 15, pc0 = tc * 15;
    const int tid = threadIdx.x;
    const int wv = tid >> 6, lane = tid & 63;
    const int ti = tid >> 4, tj = tid & 15;
    const int tl = ti & 3;
    float* wreg = smem + wv * 320;
    float* halo = smem + 1280;
    const float* inb = in + (size_t)b * 6 * 15129;
    const int irw = 2 * pr0 - 1 + 8 * wv;
    const int ic0 = 2 * pc0 - 1;
    const bool safe = (tr >= 1 && tr <= 3) && (tc >= 1 && tc <= 3);

    int off[5];
    unsigned msk = 0u;
    {
        int y = (lane >= 34) ? 1 : 0;
        int x = lane - 34 * y;
        #pragma unroll
        for (int it = 0; it < 5; ++it) {
            int gr = irw + y, gc = ic0 + x;
            bool valid = ((unsigned)gr < 123u) && ((unsigned)gc < 123u);
            off[it] = valid ? (gr * 123 + gc) : 0;
            msk |= (valid ? 1u : 0u) << it;
            x += 30; ++y;
            if (x >= 34) { x -= 34; ++y; }
        }
    }

    float acc[15];
    #pragma unroll
    for (int o = 0; o < 15; ++o) acc[o] = bias[o];

    for (int c = 0; c < 6; ++c) {
        const float* cp = inb + c * 15129;
        if (safe) {
            #pragma unroll
            for (int it = 0; it < 5; ++it) wreg[lane + it * 64] = cp[off[it]];
        } else {
            #pragma unroll
            for (int it = 0; it < 5; ++it) {
                float v = 0.0f;
                if ((msk >> it) & 1u) v = cp[off[it]];
                wreg[lane + it * 64] = v;
            }
        }
        #pragma unroll
        for (int kh = 0; kh < 3; ++kh) {
            const float* r = &wreg[(2 * tl + kh) * 34 + 2 * tj];
            float a0 = r[0], a1 = r[1], a2 = r[2];
            #pragma unroll
            for (int o = 0; o < 15; ++o) {
                const float* wr_ = &w[o * 54 + c * 9 + kh * 3];
                acc[o] = fmaf(a0, wr_[0], acc[o]);
                acc[o] = fmaf(a1, wr_[1], acc[o]);
                acc[o] = fmaf(a2, wr_[2], acc[o]);
            }
        }
    }

    if (tl == 0 && wv > 0) {
        #pragma unroll
        for (int o = 0; o < 15; ++o)
            halo[(wv - 1) * 240 + o * 16 + tj] = acc[o];
    }
    __syncthreads();

    const int gr = pr0 + ti, gc = pc0 + tj;
    const bool valid = (ti < 15) && (tj < 15) && (gr < 61) && (gc < 61);
    const bool lastrow = (tl == 3);
    const int hb = (wv < 2 ? wv : 2) * 240;
    #pragma unroll
    for (int o = 0; o < 15; ++o) {
        float c00 = acc[o];
        float c01 = __shfl(acc[o], lane + 1);
        float s10 = __shfl(acc[o], lane + 16);
        float s11 = __shfl(acc[o], lane + 17);
        float h10 = halo[hb + o * 16 + tj];
        float h11 = halo[hb + o * 16 + (tj + 1 > 15 ? 15 : tj + 1)];
        float c10 = lastrow ? h10 : s10;
        float c11 = lastrow ? h11 : s11;
        float m = fmaxf(fmaxf(fmaxf(c00, c01), fmaxf(c10, c11)), 0.0f);
        if (valid) out[(size_t)b * KP + o * 3721 + gr * 61 + gc] = f2bf(m);
    }
}

// ---------------- W1 f32 -> bf16 (padded rows), dedicated dispatch (r23-verbatim) ----------------
__global__ __launch_bounds__(256) void wcvt_k(const float* __restrict__ W,
                                              unsigned short* __restrict__ Wb) {
    const int n = blockIdx.y;
    const float* src = W + (size_t)n * FC1_K;
    unsigned int* dst = (unsigned int*)(Wb + (size_t)n * KP);
    int base = blockIdx.x * 2048 + threadIdx.x * 2;
    #pragma unroll
    for (int p = 0; p < 4; ++p) {
        int k2 = base + p * 512;
        if (k2 < FC1_K) {
            float v0 = src[k2];
            float v1 = (k2 + 1 < FC1_K) ? src[k2 + 1] : 0.0f;
            dst[k2 >> 1] = (unsigned)f2bf(v0) | ((unsigned)f2bf(v1) << 16);
        }
    }
}

// ---------------- fc1 v6 (r23-verbatim): bf16 MFMA split-K GEMM, grid 256, chunk 224.
__global__ __launch_bounds__(256) void fc1_k(const unsigned short* __restrict__ Xb,
                                             const unsigned short* __restrict__ Wb,
                                             float* __restrict__ P) {
    using short8 = __attribute__((ext_vector_type(8))) short;
    using f32x4 = __attribute__((ext_vector_type(4))) float;
    __shared__ unsigned short Xs[2][128][40];
    __shared__ unsigned short Ws[2][128][40];
    const int s = blockIdx.x;
    const int ks = s * 224;
    const int ke = min(ks + 224, FC1_K);
    const int tid = threadIdx.x;
    const int row = tid >> 1, cb = (tid & 1) * 16;
    const int wv = tid >> 6, lane = tid & 63;
    const int kb = lane >> 4, lr = lane & 15;

    f32x4 acc[2][8];
    #pragma unroll
    for (int mt = 0; mt < 2; ++mt)
        #pragma unroll
        for (int nt = 0; nt < 8; ++nt)
            acc[mt][nt] = (f32x4){0.f, 0.f, 0.f, 0.f};

    const int nsteps = (ke > ks) ? ((ke - ks + 31) >> 5) : 0;

    auto stage = [&](int buf, int st) {
        const int k0 = ks + st * 32;
        const int krem = ke - k0;
        const unsigned short* xsrc = Xb + (size_t)row * KP + k0 + cb;
        #pragma unroll
        for (int q = 0; q < 2; ++q) {
            int g = cb + q * 8;
            if (g + 8 <= krem) {
                *(uint4*)&Xs[buf][row][g] = *(const uint4*)(xsrc + q * 8);
            } else {
                #pragma unroll
                for (int jj = 0; jj < 8; ++jj)
                    Xs[buf][row][g + jj] = (g + jj < krem) ? xsrc[q * 8 + jj] : (unsigned short)0;
            }
        }
        if (row < 120) {
            const unsigned short* wsrc = Wb + (size_t)row * KP + k0 + cb;
            #pragma unroll
            for (int q = 0; q < 2; ++q) {
                int g = cb + q * 8;
                if (g + 8 <= krem) {
                    *(uint4*)&Ws[buf][row][g] = *(const uint4*)(wsrc + q * 8);
                } else {
                    #pragma unroll
                    for (int jj = 0; jj < 8; ++jj)
                        Ws[buf][row][g + jj] = (g + jj < krem) ? wsrc[q * 8 + jj] : (unsigned short)0;
                }
            }
        } else {
            uint4 z = {0u, 0u, 0u, 0u};
            *(uint4*)&Ws[buf][row][cb] = z;
            *(uint4*)&Ws[buf][row][cb + 8] = z;
        }
    };

    if (nsteps > 0) stage(0, 0);
    int cur = 0;
    for (int st = 0; st < nsteps; ++st) {
        __syncthreads();
        if (st + 1 < nsteps) stage(cur ^ 1, st + 1);
        short8 afr[2];
        #pragma unroll
        for (int mt = 0; mt < 2; ++mt)
            afr[mt] = *(const short8*)&Xs[cur][(wv * 2 + mt) * 16 + lr][kb * 8];
        #pragma unroll
        for (int nt = 0; nt < 8; ++nt) {
            short8 bfr = *(const short8*)&Ws[cur][nt * 16 + lr][kb * 8];
            #pragma unroll
            for (int mt = 0; mt < 2; ++mt)
                acc[mt][nt] = __builtin_amdgcn_mfma_f32_16x16x32_bf16(afr[mt], bfr, acc[mt][nt], 0, 0, 0);
        }
        cur ^= 1;
    }

    float* Pp = P + (size_t)s * 15360;
    #pragma unroll
    for (int mt = 0; mt < 2; ++mt)
        #pragma unroll
        for (int nt = 0; nt < 8; ++nt)
            #pragma unroll
            for (int r = 0; r < 4; ++r) {
                int m = (wv * 2 + mt) * 16 + kb * 4 + r;
                int n = nt * 16 + lr;
                if (n < 120) Pp[m * 120 + n] = acc[mt][nt][r];
            }
}

// ---------------- tail v3 (r23-verbatim): 512 threads, 4-way split reduce + heads
__global__ __launch_bounds__(512) void tail_k(const float* __restrict__ P,
                                              const float* __restrict__ f1b,
                                              const float* __restrict__ f2w,
                                              const float* __restrict__ f2b,
                                              const float* __restrict__ f3w,
                                              const float* __restrict__ f3b,
                                              const float* __restrict__ qp,
                                              float* __restrict__ out) {
    __shared__ float red[4][120];
    __shared__ float x1[120];
    __shared__ float x2[84];
    int b = blockIdx.x, tid = threadIdx.x;
    if (tid < 480) {
        int part = tid / 120;
        int n = tid - part * 120;
        const float* p = P + (size_t)b * 120 + n;
        float acc = 0.0f;
        #pragma unroll 8
        for (int s = part; s < SPLITK; s += 4)
            acc += p[(size_t)s * 15360];
        red[part][n] = acc;
    }
    __syncthreads();
    if (tid < 120)
        x1[tid] = fmaxf((red[0][tid] + red[1][tid]) + (red[2][tid] + red[3][tid]) + f1b[tid], 0.0f);
    __syncthreads();
    if (tid < 84) {
        float acc = f2b[tid];
        const float* wr = f2w + tid * 120;
        #pragma unroll 4
        for (int n = 0; n < 120; ++n) acc = fmaf(x1[n], wr[n], acc);
        x2[tid] = fmaxf(acc, 0.0f);
    }
    __syncthreads();
    if (tid == 0) {
        float x = f3b[0];
        for (int m = 0; m < 84; ++m) x = fmaf(x2[m], f3w[m], x);
        float sr[16], si[16];
        #pragma unroll
        for (int i = 0; i < 16; ++i) { sr[i] = 0.0f; si[i] = 0.0f; }
        sr[0] = 1.0f;
        float c0 = cosf(0.5f * x), s0 = sinf(0.5f * x);
        #pragma unroll
        for (int w = 0; w < 4; ++w) {
            int mask = 8 >> w;
            #pragma unroll
            for (int idx = 0; idx < 16; ++idx) {
                if (idx & mask) continue;
                int i1 = idx | mask;
                float a0r = sr[idx], a0i = si[idx], a1r = sr[i1], a1i = si[i1];
                sr[idx] = c0 * a0r - s0 * a1r;  si[idx] = c0 * a0i - s0 * a1i;
                sr[i1]  = s0 * a0r + c0 * a1r;  si[i1]  = s0 * a0i + c0 * a1i;
            }
        }
        for (int layer = 0; layer < 2; ++layer) {
            #pragma unroll
            for (int w = 0; w < 4; ++w) {
                int gi = (layer * 4 + w) * 3;
                float phi = qp[gi], th = qp[gi + 1], om = qp[gi + 2];
                float hs = 0.5f * (phi + om), hd = 0.5f * (phi - om);
                float ct = cosf(0.5f * th), st = sinf(0.5f * th);
                float chs = cosf(hs), shs = sinf(hs);
                float chd = cosf(hd), shd = sinf(hd);
                float m00r = chs * ct,  m00i = -shs * ct;
                float m01r = -chd * st, m01i = -shd * st;
                float m10r = chd * st,  m10i = -shd * st;
                float m11r = chs * ct,  m11i = shs * ct;
                int mask = 8 >> w;
                #pragma unroll
                for (int idx = 0; idx < 16; ++idx) {
                    if (idx & mask) continue;
                    int i1 = idx | mask;
                    float a0r = sr[idx], a0i = si[idx], a1r = sr[i1], a1i = si[i1];
                    sr[idx] = m00r * a0r - m00i * a0i + m01r * a1r - m01i * a1i;
                    si[idx] = m00r * a0i + m00i * a0r + m01r * a1i + m01i * a1r;
                    sr[i1]  = m10r * a0r - m10i * a0i + m11r * a1r - m11i * a1i;
                    si[i1]  = m10r * a0i + m10i * a0r + m11r * a1i + m11i * a1r;
                }
            }
            #pragma unroll
            for (int cw = 0; cw < 3; ++cw) {
                int cm = 8 >> cw, tm = 8 >> (cw + 1);
                #pragma unroll
                for (int idx = 0; idx < 16; ++idx) {
                    if ((idx & cm) && !(idx & tm)) {
                        int i1 = idx | tm;
                        float tr = sr[idx]; sr[idx] = sr[i1]; sr[i1] = tr;
                        float ti = si[idx]; si[idx] = si[i1]; si[i1] = ti;
                    }
                }
            }
        }
        float q = 0.0f;
        #pragma unroll
        for (int idx = 0; idx < 16; ++idx) {
            float p2 = sr[idx] * sr[idx] + si[idx] * si[idx];
            q += (idx < 8) ? p2 : -p2;
        }
        float pr = 0.5f * (q + 1.0f);
        out[2 * b] = pr;
        out[2 * b + 1] = 1.0f - pr;
    }
}

extern "C" void kernel_launch(void* const* d_in, const int* in_sizes, int n_in,
                              void* d_out, int out_size, void* d_ws, size_t ws_size,
                              hipStream_t stream) {
    const float* inp = (const float*)d_in[0];
    const float* c1w = (const float*)d_in[1];
    const float* c1b = (const float*)d_in[2];
    const float* c2w = (const float*)d_in[3];
    const float* c2b = (const float*)d_in[4];
    const float* f1w = (const float*)d_in[5];
    const float* f1b = (const float*)d_in[6];
    const float* f2w = (const float*)d_in[7];
    const float* f2b = (const float*)d_in[8];
    const float* f3w = (const float*)d_in[9];
    const float* f3b = (const float*)d_in[10];
    const float* qp  = (const float*)d_in[11];
    float* out = (float*)d_out;
    float* ws = (float*)d_ws;

    // ws layout (float units):
    //   B  (pool1 out, f32)   @ 0          : 11,619,072
    //   Db (pool2 out, bf16)  @ 11,619,072 : 128*KP shorts = 3,572,224 f
    //   P  (fc1 partials,f32) @ 15,191,296 : 256*128*120 = 3,932,160
    //   Wb (W1 bf16)          @ 19,123,456 : 120*KP shorts = 3,348,960 f
    float* B = ws;
    unsigned short* Db = (unsigned short*)(ws + 11619072);
    float* P = ws + 15191296;
    unsigned short* Wb = (unsigned short*)(ws + 19123456);

    wcvt_k<<<dim3(28, 120), 256, 0, stream>>>(f1w, Wb);
    conv1f_k<<<dim3(9, 9, 128), 256, 0, stream>>>(inp, c1w, c1b, B);
    conv2f_k<<<dim3(5, 5, 128), 256, 0, stream>>>(B, c2w, c2b, Db);
    fc1_k<<<dim3(SPLITK), 256, 0, stream>>>(Db, Wb, P);
    tail_k<<<128, 512, 0, stream>>>(P, f1b, f2w, f2b, f3w, f3b, qp, out);
}

// Round 25
// 141.776 us; speedup vs baseline: 1.4503x; 1.4503x over previous
//
#include <hip/hip_runtime.h>

#define SPLITK 256
#define FC1_K 55815
#define KP 55816  // padded bf16 row stride (16B-aligned rows)

__device__ __forceinline__ unsigned short f2bf(float f) {
    unsigned u = __float_as_uint(f);
    return (unsigned short)((u + 0x7FFFu + ((u >> 16) & 1u)) >> 16);  // RNE
}
__device__ __forceinline__ float bf2f(unsigned short h) {
    unsigned u = ((unsigned)h) << 16;
    return __uint_as_float(u);
}

// ============ conv1 + relu + pool1 fused (v6 structure; B output now bf16) ============
__global__ __launch_bounds__(256) void conv1f_k(const float* __restrict__ in,
                                                const float* __restrict__ w,
                                                const float* __restrict__ bias,
                                                unsigned short* __restrict__ out) {
    __shared__ float sbuf[4608];
    const int tc = blockIdx.x, tr = blockIdx.y, b = blockIdx.z;
    const int pr0 = tr * 31, pc0 = tc * 31;
    const int tid = threadIdx.x;
    const int i = tid >> 4, j = tid & 15;
    const float* inb = in + (size_t)b * 187500;
    const int ir0 = 2 * pr0 - 1, ic0 = 2 * pc0 - 1;

    float acc[6][2][2];
    #pragma unroll
    for (int o = 0; o < 6; ++o) {
        float bv = bias[o];
        acc[o][0][0] = bv; acc[o][0][1] = bv; acc[o][1][0] = bv; acc[o][1][1] = bv;
    }

    float stg[18];
    auto load_ch = [&](int c) {
        const float* cp = inb + c * 62500;
        int y = tid / 68;
        int x = tid - y * 68;
        #pragma unroll
        for (int it = 0; it < 18; ++it) {
            int gr = ir0 + y, gc = ic0 + x;
            float v = 0.0f;
            if ((unsigned)gr < 250u && (unsigned)gc < 250u)
                v = cp[gr * 250 + gc];
            stg[it] = v;
            x += 52; y += 3;
            if (x >= 68) { x -= 68; ++y; }
        }
    };
    auto write_ch = [&]() {
        #pragma unroll
        for (int it = 0; it < 18; ++it) sbuf[tid + it * 256] = stg[it];
    };
    auto compute_ch = [&](int c) {
        #pragma unroll
        for (int wr = 0; wr < 7; ++wr) {
            const float* rp = &sbuf[(4 * i + wr) * 68 + 4 * j];
            float row[7];
            float4 v4 = *(const float4*)rp;
            float2 v2 = *(const float2*)(rp + 4);
            row[0] = v4.x; row[1] = v4.y; row[2] = v4.z; row[3] = v4.w;
            row[4] = v2.x; row[5] = v2.y; row[6] = rp[6];
            #pragma unroll
            for (int o = 0; o < 6; ++o) {
                #pragma unroll
                for (int kw = 0; kw < 5; ++kw) {
                    if (wr <= 4) {
                        float wv = w[o * 75 + c * 25 + wr * 5 + kw];
                        acc[o][0][0] = fmaf(row[kw], wv, acc[o][0][0]);
                        acc[o][0][1] = fmaf(row[kw + 2], wv, acc[o][0][1]);
                    }
                    if (wr >= 2) {
                        float wv = w[o * 75 + c * 25 + (wr - 2) * 5 + kw];
                        acc[o][1][0] = fmaf(row[kw], wv, acc[o][1][0]);
                        acc[o][1][1] = fmaf(row[kw + 2], wv, acc[o][1][1]);
                    }
                }
            }
        }
    };

    load_ch(0); write_ch();
    __syncthreads();
    load_ch(1); compute_ch(0);
    __syncthreads();
    write_ch();
    __syncthreads();
    load_ch(2); compute_ch(1);
    __syncthreads();
    write_ch();
    __syncthreads();
    compute_ch(2);
    __syncthreads();

    const int gr0 = pr0 + 2 * i, gc0 = pc0 + 2 * j;
    const bool r1in = (2 * i + 1 < 31) && (gr0 + 1 < 123);
    const bool c1in = (2 * j + 1 < 31) && (gc0 + 1 < 123);
    const bool r0in = gr0 < 123, c0in = gc0 < 123;
    #pragma unroll
    for (int g = 0; g < 2; ++g) {
        #pragma unroll
        for (int oo = 0; oo < 3; ++oo)
            #pragma unroll
            for (int di = 0; di < 2; ++di)
                #pragma unroll
                for (int dj = 0; dj < 2; ++dj)
                    sbuf[(oo * 32 + 2 * i + di) * 33 + (2 * j + dj)] =
                        fmaxf(acc[g * 3 + oo][di][dj], 0.0f);
        __syncthreads();
        #pragma unroll
        for (int oo = 0; oo < 3; ++oo) {
            int o = g * 3 + oo;
            const float* p0 = &sbuf[(oo * 32 + 2 * i) * 33 + 2 * j];
            float c00 = p0[0],  c01 = p0[1],  c02 = p0[2];
            float c10 = p0[33], c11 = p0[34], c12 = p0[35];
            float c20 = p0[66], c21 = p0[67], c22 = p0[68];
            unsigned short* orow = out + ((size_t)(b * 6 + o) * 123 + gr0) * 123 + gc0;
            if (r0in && c0in) orow[0]   = f2bf(fmaxf(fmaxf(c00, c01), fmaxf(c10, c11)));
            if (r0in && c1in) orow[1]   = f2bf(fmaxf(fmaxf(c01, c02), fmaxf(c11, c12)));
            if (r1in && c0in) orow[123] = f2bf(fmaxf(fmaxf(c10, c11), fmaxf(c20, c21)));
            if (r1in && c1in) orow[124] = f2bf(fmaxf(fmaxf(c11, c12), fmaxf(c21, c22)));
        }
        __syncthreads();
    }
}

// ============ conv2 + relu + pool2 fused (v5 structure; B input now bf16) ============
__global__ __launch_bounds__(256) void conv2f_k(const unsigned short* __restrict__ in,
                                                const float* __restrict__ w,
                                                const float* __restrict__ bias,
                                                unsigned short* __restrict__ out) {
    __shared__ float smem[2000];
    const int tc = blockIdx.x, tr = blockIdx.y, b = blockIdx.z;
    const int pr0 = tr * 15, pc0 = tc * 15;
    const int tid = threadIdx.x;
    const int wv = tid >> 6, lane = tid & 63;
    const int ti = tid >> 4, tj = tid & 15;
    const int tl = ti & 3;
    float* wreg = smem + wv * 320;
    float* halo = smem + 1280;
    const unsigned short* inb = in + (size_t)b * 6 * 15129;
    const int irw = 2 * pr0 - 1 + 8 * wv;
    const int ic0 = 2 * pc0 - 1;
    const bool safe = (tr >= 1 && tr <= 3) && (tc >= 1 && tc <= 3);

    int off[5];
    unsigned msk = 0u;
    {
        int y = (lane >= 34) ? 1 : 0;
        int x = lane - 34 * y;
        #pragma unroll
        for (int it = 0; it < 5; ++it) {
            int gr = irw + y, gc = ic0 + x;
            bool valid = ((unsigned)gr < 123u) && ((unsigned)gc < 123u);
            off[it] = valid ? (gr * 123 + gc) : 0;
            msk |= (valid ? 1u : 0u) << it;
            x += 30; ++y;
            if (x >= 34) { x -= 34; ++y; }
        }
    }

    float acc[15];
    #pragma unroll
    for (int o = 0; o < 15; ++o) acc[o] = bias[o];

    for (int c = 0; c < 6; ++c) {
        const unsigned short* cp = inb + c * 15129;
        if (safe) {
            #pragma unroll
            for (int it = 0; it < 5; ++it) wreg[lane + it * 64] = bf2f(cp[off[it]]);
        } else {
            #pragma unroll
            for (int it = 0; it < 5; ++it) {
                float v = 0.0f;
                if ((msk >> it) & 1u) v = bf2f(cp[off[it]]);
                wreg[lane + it * 64] = v;
            }
        }
        #pragma unroll
        for (int kh = 0; kh < 3; ++kh) {
            const float* r = &wreg[(2 * tl + kh) * 34 + 2 * tj];
            float a0 = r[0], a1 = r[1], a2 = r[2];
            #pragma unroll
            for (int o = 0; o < 15; ++o) {
                const float* wr_ = &w[o * 54 + c * 9 + kh * 3];
                acc[o] = fmaf(a0, wr_[0], acc[o]);
                acc[o] = fmaf(a1, wr_[1], acc[o]);
                acc[o] = fmaf(a2, wr_[2], acc[o]);
            }
        }
    }

    if (tl == 0 && wv > 0) {
        #pragma unroll
        for (int o = 0; o < 15; ++o)
            halo[(wv - 1) * 240 + o * 16 + tj] = acc[o];
    }
    __syncthreads();

    const int gr = pr0 + ti, gc = pc0 + tj;
    const bool valid = (ti < 15) && (tj < 15) && (gr < 61) && (gc < 61);
    const bool lastrow = (tl == 3);
    const int hb = (wv < 2 ? wv : 2) * 240;
    #pragma unroll
    for (int o = 0; o < 15; ++o) {
        float c00 = acc[o];
        float c01 = __shfl(acc[o], lane + 1);
        float s10 = __shfl(acc[o], lane + 16);
        float s11 = __shfl(acc[o], lane + 17);
        float h10 = halo[hb + o * 16 + tj];
        float h11 = halo[hb + o * 16 + (tj + 1 > 15 ? 15 : tj + 1)];
        float c10 = lastrow ? h10 : s10;
        float c11 = lastrow ? h11 : s11;
        float m = fmaxf(fmaxf(fmaxf(c00, c01), fmaxf(c10, c11)), 0.0f);
        if (valid) out[(size_t)b * KP + o * 3721 + gr * 61 + gc] = f2bf(m);
    }
}

// ---------------- W1 f32 -> bf16 (padded rows), dedicated dispatch (r23-verbatim) ----------------
__global__ __launch_bounds__(256) void wcvt_k(const float* __restrict__ W,
                                              unsigned short* __restrict__ Wb) {
    const int n = blockIdx.y;
    const float* src = W + (size_t)n * FC1_K;
    unsigned int* dst = (unsigned int*)(Wb + (size_t)n * KP);
    int base = blockIdx.x * 2048 + threadIdx.x * 2;
    #pragma unroll
    for (int p = 0; p < 4; ++p) {
        int k2 = base + p * 512;
        if (k2 < FC1_K) {
            float v0 = src[k2];
            float v1 = (k2 + 1 < FC1_K) ? src[k2 + 1] : 0.0f;
            dst[k2 >> 1] = (unsigned)f2bf(v0) | ((unsigned)f2bf(v1) << 16);
        }
    }
}

// ---------------- fc1 v6 (r23-verbatim): bf16 MFMA split-K GEMM, grid 256, chunk 224.
__global__ __launch_bounds__(256) void fc1_k(const unsigned short* __restrict__ Xb,
                                             const unsigned short* __restrict__ Wb,
                                             float* __restrict__ P) {
    using short8 = __attribute__((ext_vector_type(8))) short;
    using f32x4 = __attribute__((ext_vector_type(4))) float;
    __shared__ unsigned short Xs[2][128][40];
    __shared__ unsigned short Ws[2][128][40];
    const int s = blockIdx.x;
    const int ks = s * 224;
    const int ke = min(ks + 224, FC1_K);
    const int tid = threadIdx.x;
    const int row = tid >> 1, cb = (tid & 1) * 16;
    const int wv = tid >> 6, lane = tid & 63;
    const int kb = lane >> 4, lr = lane & 15;

    f32x4 acc[2][8];
    #pragma unroll
    for (int mt = 0; mt < 2; ++mt)
        #pragma unroll
        for (int nt = 0; nt < 8; ++nt)
            acc[mt][nt] = (f32x4){0.f, 0.f, 0.f, 0.f};

    const int nsteps = (ke > ks) ? ((ke - ks + 31) >> 5) : 0;

    auto stage = [&](int buf, int st) {
        const int k0 = ks + st * 32;
        const int krem = ke - k0;
        const unsigned short* xsrc = Xb + (size_t)row * KP + k0 + cb;
        #pragma unroll
        for (int q = 0; q < 2; ++q) {
            int g = cb + q * 8;
            if (g + 8 <= krem) {
                *(uint4*)&Xs[buf][row][g] = *(const uint4*)(xsrc + q * 8);
            } else {
                #pragma unroll
                for (int jj = 0; jj < 8; ++jj)
                    Xs[buf][row][g + jj] = (g + jj < krem) ? xsrc[q * 8 + jj] : (unsigned short)0;
            }
        }
        if (row < 120) {
            const unsigned short* wsrc = Wb + (size_t)row * KP + k0 + cb;
            #pragma unroll
            for (int q = 0; q < 2; ++q) {
                int g = cb + q * 8;
                if (g + 8 <= krem) {
                    *(uint4*)&Ws[buf][row][g] = *(const uint4*)(wsrc + q * 8);
                } else {
                    #pragma unroll
                    for (int jj = 0; jj < 8; ++jj)
                        Ws[buf][row][g + jj] = (g + jj < krem) ? wsrc[q * 8 + jj] : (unsigned short)0;
                }
            }
        } else {
            uint4 z = {0u, 0u, 0u, 0u};
            *(uint4*)&Ws[buf][row][cb] = z;
            *(uint4*)&Ws[buf][row][cb + 8] = z;
        }
    };

    if (nsteps > 0) stage(0, 0);
    int cur = 0;
    for (int st = 0; st < nsteps; ++st) {
        __syncthreads();
        if (st + 1 < nsteps) stage(cur ^ 1, st + 1);
        short8 afr[2];
        #pragma unroll
        for (int mt = 0; mt < 2; ++mt)
            afr[mt] = *(const short8*)&Xs[cur][(wv * 2 + mt) * 16 + lr][kb * 8];
        #pragma unroll
        for (int nt = 0; nt < 8; ++nt) {
            short8 bfr = *(const short8*)&Ws[cur][nt * 16 + lr][kb * 8];
            #pragma unroll
            for (int mt = 0; mt < 2; ++mt)
                acc[mt][nt] = __builtin_amdgcn_mfma_f32_16x16x32_bf16(afr[mt], bfr, acc[mt][nt], 0, 0, 0);
        }
        cur ^= 1;
    }

    float* Pp = P + (size_t)s * 15360;
    #pragma unroll
    for (int mt = 0; mt < 2; ++mt)
        #pragma unroll
        for (int nt = 0; nt < 8; ++nt)
            #pragma unroll
            for (int r = 0; r < 4; ++r) {
                int m = (wv * 2 + mt) * 16 + kb * 4 + r;
                int n = nt * 16 + lr;
                if (n < 120) Pp[m * 120 + n] = acc[mt][nt][r];
            }
}

// ---------------- tail v3 (r23-verbatim): 512 threads, 4-way split reduce + heads
__global__ __launch_bounds__(512) void tail_k(const float* __restrict__ P,
                                              const float* __restrict__ f1b,
                                              const float* __restrict__ f2w,
                                              const float* __restrict__ f2b,
                                              const float* __restrict__ f3w,
                                              const float* __restrict__ f3b,
                                              const float* __restrict__ qp,
                                              float* __restrict__ out) {
    __shared__ float red[4][120];
    __shared__ float x1[120];
    __shared__ float x2[84];
    int b = blockIdx.x, tid = threadIdx.x;
    if (tid < 480) {
        int part = tid / 120;
        int n = tid - part * 120;
        const float* p = P + (size_t)b * 120 + n;
        float acc = 0.0f;
        #pragma unroll 8
        for (int s = part; s < SPLITK; s += 4)
            acc += p[(size_t)s * 15360];
        red[part][n] = acc;
    }
    __syncthreads();
    if (tid < 120)
        x1[tid] = fmaxf((red[0][tid] + red[1][tid]) + (red[2][tid] + red[3][tid]) + f1b[tid], 0.0f);
    __syncthreads();
    if (tid < 84) {
        float acc = f2b[tid];
        const float* wr = f2w + tid * 120;
        #pragma unroll 4
        for (int n = 0; n < 120; ++n) acc = fmaf(x1[n], wr[n], acc);
        x2[tid] = fmaxf(acc, 0.0f);
    }
    __syncthreads();
    if (tid == 0) {
        float x = f3b[0];
        for (int m = 0; m < 84; ++m) x = fmaf(x2[m], f3w[m], x);
        float sr[16], si[16];
        #pragma unroll
        for (int i = 0; i < 16; ++i) { sr[i] = 0.0f; si[i] = 0.0f; }
        sr[0] = 1.0f;
        float c0 = cosf(0.5f * x), s0 = sinf(0.5f * x);
        #pragma unroll
        for (int w = 0; w < 4; ++w) {
            int mask = 8 >> w;
            #pragma unroll
            for (int idx = 0; idx < 16; ++idx) {
                if (idx & mask) continue;
                int i1 = idx | mask;
                float a0r = sr[idx], a0i = si[idx], a1r = sr[i1], a1i = si[i1];
                sr[idx] = c0 * a0r - s0 * a1r;  si[idx] = c0 * a0i - s0 * a1i;
                sr[i1]  = s0 * a0r + c0 * a1r;  si[i1]  = s0 * a0i + c0 * a1i;
            }
        }
        for (int layer = 0; layer < 2; ++layer) {
            #pragma unroll
            for (int w = 0; w < 4; ++w) {
                int gi = (layer * 4 + w) * 3;
                float phi = qp[gi], th = qp[gi + 1], om = qp[gi + 2];
                float hs = 0.5f * (phi + om), hd = 0.5f * (phi - om);
                float ct = cosf(0.5f * th), st = sinf(0.5f * th);
                float chs = cosf(hs), shs = sinf(hs);
                float chd = cosf(hd), shd = sinf(hd);
                float m00r = chs * ct,  m00i = -shs * ct;
                float m01r = -chd * st, m01i = -shd * st;
                float m10r = chd * st,  m10i = -shd * st;
                float m11r = chs * ct,  m11i = shs * ct;
                int mask = 8 >> w;
                #pragma unroll
                for (int idx = 0; idx < 16; ++idx) {
                    if (idx & mask) continue;
                    int i1 = idx | mask;
                    float a0r = sr[idx], a0i = si[idx], a1r = sr[i1], a1i = si[i1];
                    sr[idx] = m00r * a0r - m00i * a0i + m01r * a1r - m01i * a1i;
                    si[idx] = m00r * a0i + m00i * a0r + m01r * a1i + m01i * a1r;
                    sr[i1]  = m10r * a0r - m10i * a0i + m11r * a1r - m11i * a1i;
                    si[i1]  = m10r * a0i + m10i * a0r + m11r * a1i + m11i * a1r;
                }
            }
            #pragma unroll
            for (int cw = 0; cw < 3; ++cw) {
                int cm = 8 >> cw, tm = 8 >> (cw + 1);
                #pragma unroll
                for (int idx = 0; idx < 16; ++idx) {
                    if ((idx & cm) && !(idx & tm)) {
                        int i1 = idx | tm;
                        float tr = sr[idx]; sr[idx] = sr[i1]; sr[i1] = tr;
                        float ti = si[idx]; si[idx] = si[i1]; si[i1] = ti;
                    }
                }
            }
        }
        float q = 0.0f;
        #pragma unroll
        for (int idx = 0; idx < 16; ++idx) {
            float p2 = sr[idx] * sr[idx] + si[idx] * si[idx];
            q += (idx < 8) ? p2 : -p2;
        }
        float pr = 0.5f * (q + 1.0f);
        out[2 * b] = pr;
        out[2 * b + 1] = 1.0f - pr;
    }
}

extern "C" void kernel_launch(void* const* d_in, const int* in_sizes, int n_in,
                              void* d_out, int out_size, void* d_ws, size_t ws_size,
                              hipStream_t stream) {
    const float* inp = (const float*)d_in[0];
    const float* c1w = (const float*)d_in[1];
    const float* c1b = (const float*)d_in[2];
    const float* c2w = (const float*)d_in[3];
    const float* c2b = (const float*)d_in[4];
    const float* f1w = (const float*)d_in[5];
    const float* f1b = (const float*)d_in[6];
    const float* f2w = (const float*)d_in[7];
    const float* f2b = (const float*)d_in[8];
    const float* f3w = (const float*)d_in[9];
    const float* f3b = (const float*)d_in[10];
    const float* qp  = (const float*)d_in[11];
    float* out = (float*)d_out;
    float* ws = (float*)d_ws;

    // ws layout (float units):
    //   Bb (pool1 out, bf16)  @ 0          : 128*6*123*123 shorts = 5,809,536 f
    //   Db (pool2 out, bf16)  @ 5,809,536  : 128*KP shorts = 3,572,224 f
    //   P  (fc1 partials,f32) @ 9,381,760  : 256*128*120 = 3,932,160
    //   Wb (W1 bf16)          @ 13,313,920 : 120*KP shorts = 3,348,960 f
    unsigned short* Bb = (unsigned short*)ws;
    unsigned short* Db = (unsigned short*)(ws + 5809536);
    float* P = ws + 9381760;
    unsigned short* Wb = (unsigned short*)(ws + 13313920);

    wcvt_k<<<dim3(28, 120), 256, 0, stream>>>(f1w, Wb);
    conv1f_k<<<dim3(4, 4, 128), 256, 0, stream>>>(inp, c1w, c1b, Bb);
    conv2f_k<<<dim3(5, 5, 128), 256, 0, stream>>>(Bb, c2w, c2b, Db);
    fc1_k<<<dim3(SPLITK), 256, 0, stream>>>(Db, Wb, P);
    tail_k<<<128, 512, 0, stream>>>(P, f1b, f2w, f2b, f3w, f3b, qp, out);
}

// Round 26
// 131.402 us; speedup vs baseline: 1.5648x; 1.0789x over previous
//
#include <hip/hip_runtime.h>

#define SPLITK 256
#define FC1_K 55815
#define KP 55816  // padded bf16 row stride (16B-aligned rows)

__device__ __forceinline__ unsigned short f2bf(float f) {
    unsigned u = __float_as_uint(f);
    return (unsigned short)((u + 0x7FFFu + ((u >> 16) & 1u)) >> 16);  // RNE
}
__device__ __forceinline__ float bf2f(unsigned short h) {
    unsigned u = ((unsigned)h) << 16;
    return __uint_as_float(u);
}

// ============ conv1 + relu + pool1 fused (v6 + interior fast path; bf16 B output) ============
// Interior blocks (tr,tc in {1,2}: window rows 2*31*tr-1..+66 all in [0,250)) skip bounds
// masking in the stage loop (block-uniform branch; y/x walk unchanged, no hoisted offsets).
__global__ __launch_bounds__(256) void conv1f_k(const float* __restrict__ in,
                                                const float* __restrict__ w,
                                                const float* __restrict__ bias,
                                                unsigned short* __restrict__ out) {
    __shared__ float sbuf[4608];
    const int tc = blockIdx.x, tr = blockIdx.y, b = blockIdx.z;
    const int pr0 = tr * 31, pc0 = tc * 31;
    const int tid = threadIdx.x;
    const int i = tid >> 4, j = tid & 15;
    const float* inb = in + (size_t)b * 187500;
    const int ir0 = 2 * pr0 - 1, ic0 = 2 * pc0 - 1;
    const bool safe = (tr == 1 || tr == 2) && (tc == 1 || tc == 2);

    float acc[6][2][2];
    #pragma unroll
    for (int o = 0; o < 6; ++o) {
        float bv = bias[o];
        acc[o][0][0] = bv; acc[o][0][1] = bv; acc[o][1][0] = bv; acc[o][1][1] = bv;
    }

    float stg[18];
    auto load_ch = [&](int c) {
        const float* cp = inb + c * 62500;
        int y = tid / 68;
        int x = tid - y * 68;
        if (safe) {
            #pragma unroll
            for (int it = 0; it < 18; ++it) {
                stg[it] = cp[(ir0 + y) * 250 + (ic0 + x)];
                x += 52; y += 3;
                if (x >= 68) { x -= 68; ++y; }
            }
        } else {
            #pragma unroll
            for (int it = 0; it < 18; ++it) {
                int gr = ir0 + y, gc = ic0 + x;
                float v = 0.0f;
                if ((unsigned)gr < 250u && (unsigned)gc < 250u)
                    v = cp[gr * 250 + gc];
                stg[it] = v;
                x += 52; y += 3;
                if (x >= 68) { x -= 68; ++y; }
            }
        }
    };
    auto write_ch = [&]() {
        #pragma unroll
        for (int it = 0; it < 18; ++it) sbuf[tid + it * 256] = stg[it];
    };
    auto compute_ch = [&](int c) {
        #pragma unroll
        for (int wr = 0; wr < 7; ++wr) {
            const float* rp = &sbuf[(4 * i + wr) * 68 + 4 * j];
            float row[7];
            float4 v4 = *(const float4*)rp;
            float2 v2 = *(const float2*)(rp + 4);
            row[0] = v4.x; row[1] = v4.y; row[2] = v4.z; row[3] = v4.w;
            row[4] = v2.x; row[5] = v2.y; row[6] = rp[6];
            #pragma unroll
            for (int o = 0; o < 6; ++o) {
                #pragma unroll
                for (int kw = 0; kw < 5; ++kw) {
                    if (wr <= 4) {
                        float wv = w[o * 75 + c * 25 + wr * 5 + kw];
                        acc[o][0][0] = fmaf(row[kw], wv, acc[o][0][0]);
                        acc[o][0][1] = fmaf(row[kw + 2], wv, acc[o][0][1]);
                    }
                    if (wr >= 2) {
                        float wv = w[o * 75 + c * 25 + (wr - 2) * 5 + kw];
                        acc[o][1][0] = fmaf(row[kw], wv, acc[o][1][0]);
                        acc[o][1][1] = fmaf(row[kw + 2], wv, acc[o][1][1]);
                    }
                }
            }
        }
    };

    load_ch(0); write_ch();
    __syncthreads();
    load_ch(1); compute_ch(0);
    __syncthreads();
    write_ch();
    __syncthreads();
    load_ch(2); compute_ch(1);
    __syncthreads();
    write_ch();
    __syncthreads();
    compute_ch(2);
    __syncthreads();

    const int gr0 = pr0 + 2 * i, gc0 = pc0 + 2 * j;
    const bool r1in = (2 * i + 1 < 31) && (gr0 + 1 < 123);
    const bool c1in = (2 * j + 1 < 31) && (gc0 + 1 < 123);
    const bool r0in = gr0 < 123, c0in = gc0 < 123;
    #pragma unroll
    for (int g = 0; g < 2; ++g) {
        #pragma unroll
        for (int oo = 0; oo < 3; ++oo)
            #pragma unroll
            for (int di = 0; di < 2; ++di)
                #pragma unroll
                for (int dj = 0; dj < 2; ++dj)
                    sbuf[(oo * 32 + 2 * i + di) * 33 + (2 * j + dj)] =
                        fmaxf(acc[g * 3 + oo][di][dj], 0.0f);
        __syncthreads();
        #pragma unroll
        for (int oo = 0; oo < 3; ++oo) {
            int o = g * 3 + oo;
            const float* p0 = &sbuf[(oo * 32 + 2 * i) * 33 + 2 * j];
            float c00 = p0[0],  c01 = p0[1],  c02 = p0[2];
            float c10 = p0[33], c11 = p0[34], c12 = p0[35];
            float c20 = p0[66], c21 = p0[67], c22 = p0[68];
            unsigned short* orow = out + ((size_t)(b * 6 + o) * 123 + gr0) * 123 + gc0;
            if (r0in && c0in) orow[0]   = f2bf(fmaxf(fmaxf(c00, c01), fmaxf(c10, c11)));
            if (r0in && c1in) orow[1]   = f2bf(fmaxf(fmaxf(c01, c02), fmaxf(c11, c12)));
            if (r1in && c0in) orow[123] = f2bf(fmaxf(fmaxf(c10, c11), fmaxf(c20, c21)));
            if (r1in && c1in) orow[124] = f2bf(fmaxf(fmaxf(c11, c12), fmaxf(c21, c22)));
        }
        __syncthreads();
    }
}

// ============ conv2 + relu + pool2 fused (r25-verbatim; bf16 in/out) ============
__global__ __launch_bounds__(256) void conv2f_k(const unsigned short* __restrict__ in,
                                                const float* __restrict__ w,
                                                const float* __restrict__ bias,
                                                unsigned short* __restrict__ out) {
    __shared__ float smem[2000];
    const int tc = blockIdx.x, tr = blockIdx.y, b = blockIdx.z;
    const int pr0 = tr * 15, pc0 = tc * 15;
    const int tid = threadIdx.x;
    const int wv = tid >> 6, lane = tid & 63;
    const int ti = tid >> 4, tj = tid & 15;
    const int tl = ti & 3;
    float* wreg = smem + wv * 320;
    float* halo = smem + 1280;
    const unsigned short* inb = in + (size_t)b * 6 * 15129;
    const int irw = 2 * pr0 - 1 + 8 * wv;
    const int ic0 = 2 * pc0 - 1;
    const bool safe = (tr >= 1 && tr <= 3) && (tc >= 1 && tc <= 3);

    int off[5];
    unsigned msk = 0u;
    {
        int y = (lane >= 34) ? 1 : 0;
        int x = lane - 34 * y;
        #pragma unroll
        for (int it = 0; it < 5; ++it) {
            int gr = irw + y, gc = ic0 + x;
            bool valid = ((unsigned)gr < 123u) && ((unsigned)gc < 123u);
            off[it] = valid ? (gr * 123 + gc) : 0;
            msk |= (valid ? 1u : 0u) << it;
            x += 30; ++y;
            if (x >= 34) { x -= 34; ++y; }
        }
    }

    float acc[15];
    #pragma unroll
    for (int o = 0; o < 15; ++o) acc[o] = bias[o];

    for (int c = 0; c < 6; ++c) {
        const unsigned short* cp = inb + c * 15129;
        if (safe) {
            #pragma unroll
            for (int it = 0; it < 5; ++it) wreg[lane + it * 64] = bf2f(cp[off[it]]);
        } else {
            #pragma unroll
            for (int it = 0; it < 5; ++it) {
                float v = 0.0f;
                if ((msk >> it) & 1u) v = bf2f(cp[off[it]]);
                wreg[lane + it * 64] = v;
            }
        }
        #pragma unroll
        for (int kh = 0; kh < 3; ++kh) {
            const float* r = &wreg[(2 * tl + kh) * 34 + 2 * tj];
            float a0 = r[0], a1 = r[1], a2 = r[2];
            #pragma unroll
            for (int o = 0; o < 15; ++o) {
                const float* wr_ = &w[o * 54 + c * 9 + kh * 3];
                acc[o] = fmaf(a0, wr_[0], acc[o]);
                acc[o] = fmaf(a1, wr_[1], acc[o]);
                acc[o] = fmaf(a2, wr_[2], acc[o]);
            }
        }
    }

    if (tl == 0 && wv > 0) {
        #pragma unroll
        for (int o = 0; o < 15; ++o)
            halo[(wv - 1) * 240 + o * 16 + tj] = acc[o];
    }
    __syncthreads();

    const int gr = pr0 + ti, gc = pc0 + tj;
    const bool valid = (ti < 15) && (tj < 15) && (gr < 61) && (gc < 61);
    const bool lastrow = (tl == 3);
    const int hb = (wv < 2 ? wv : 2) * 240;
    #pragma unroll
    for (int o = 0; o < 15; ++o) {
        float c00 = acc[o];
        float c01 = __shfl(acc[o], lane + 1);
        float s10 = __shfl(acc[o], lane + 16);
        float s11 = __shfl(acc[o], lane + 17);
        float h10 = halo[hb + o * 16 + tj];
        float h11 = halo[hb + o * 16 + (tj + 1 > 15 ? 15 : tj + 1)];
        float c10 = lastrow ? h10 : s10;
        float c11 = lastrow ? h11 : s11;
        float m = fmaxf(fmaxf(fmaxf(c00, c01), fmaxf(c10, c11)), 0.0f);
        if (valid) out[(size_t)b * KP + o * 3721 + gr * 61 + gc] = f2bf(m);
    }
}

// ---------------- W1 f32 -> bf16 (padded rows), dedicated dispatch (r25-verbatim) ----------------
__global__ __launch_bounds__(256) void wcvt_k(const float* __restrict__ W,
                                              unsigned short* __restrict__ Wb) {
    const int n = blockIdx.y;
    const float* src = W + (size_t)n * FC1_K;
    unsigned int* dst = (unsigned int*)(Wb + (size_t)n * KP);
    int base = blockIdx.x * 2048 + threadIdx.x * 2;
    #pragma unroll
    for (int p = 0; p < 4; ++p) {
        int k2 = base + p * 512;
        if (k2 < FC1_K) {
            float v0 = src[k2];
            float v1 = (k2 + 1 < FC1_K) ? src[k2 + 1] : 0.0f;
            dst[k2 >> 1] = (unsigned)f2bf(v0) | ((unsigned)f2bf(v1) << 16);
        }
    }
}

// ---------------- fc1 v6 (r25-verbatim): bf16 MFMA split-K GEMM, grid 256, chunk 224.
__global__ __launch_bounds__(256) void fc1_k(const unsigned short* __restrict__ Xb,
                                             const unsigned short* __restrict__ Wb,
                                             float* __restrict__ P) {
    using short8 = __attribute__((ext_vector_type(8))) short;
    using f32x4 = __attribute__((ext_vector_type(4))) float;
    __shared__ unsigned short Xs[2][128][40];
    __shared__ unsigned short Ws[2][128][40];
    const int s = blockIdx.x;
    const int ks = s * 224;
    const int ke = min(ks + 224, FC1_K);
    const int tid = threadIdx.x;
    const int row = tid >> 1, cb = (tid & 1) * 16;
    const int wv = tid >> 6, lane = tid & 63;
    const int kb = lane >> 4, lr = lane & 15;

    f32x4 acc[2][8];
    #pragma unroll
    for (int mt = 0; mt < 2; ++mt)
        #pragma unroll
        for (int nt = 0; nt < 8; ++nt)
            acc[mt][nt] = (f32x4){0.f, 0.f, 0.f, 0.f};

    const int nsteps = (ke > ks) ? ((ke - ks + 31) >> 5) : 0;

    auto stage = [&](int buf, int st) {
        const int k0 = ks + st * 32;
        const int krem = ke - k0;
        const unsigned short* xsrc = Xb + (size_t)row * KP + k0 + cb;
        #pragma unroll
        for (int q = 0; q < 2; ++q) {
            int g = cb + q * 8;
            if (g + 8 <= krem) {
                *(uint4*)&Xs[buf][row][g] = *(const uint4*)(xsrc + q * 8);
            } else {
                #pragma unroll
                for (int jj = 0; jj < 8; ++jj)
                    Xs[buf][row][g + jj] = (g + jj < krem) ? xsrc[q * 8 + jj] : (unsigned short)0;
            }
        }
        if (row < 120) {
            const unsigned short* wsrc = Wb + (size_t)row * KP + k0 + cb;
            #pragma unroll
            for (int q = 0; q < 2; ++q) {
                int g = cb + q * 8;
                if (g + 8 <= krem) {
                    *(uint4*)&Ws[buf][row][g] = *(const uint4*)(wsrc + q * 8);
                } else {
                    #pragma unroll
                    for (int jj = 0; jj < 8; ++jj)
                        Ws[buf][row][g + jj] = (g + jj < krem) ? wsrc[q * 8 + jj] : (unsigned short)0;
                }
            }
        } else {
            uint4 z = {0u, 0u, 0u, 0u};
            *(uint4*)&Ws[buf][row][cb] = z;
            *(uint4*)&Ws[buf][row][cb + 8] = z;
        }
    };

    if (nsteps > 0) stage(0, 0);
    int cur = 0;
    for (int st = 0; st < nsteps; ++st) {
        __syncthreads();
        if (st + 1 < nsteps) stage(cur ^ 1, st + 1);
        short8 afr[2];
        #pragma unroll
        for (int mt = 0; mt < 2; ++mt)
            afr[mt] = *(const short8*)&Xs[cur][(wv * 2 + mt) * 16 + lr][kb * 8];
        #pragma unroll
        for (int nt = 0; nt < 8; ++nt) {
            short8 bfr = *(const short8*)&Ws[cur][nt * 16 + lr][kb * 8];
            #pragma unroll
            for (int mt = 0; mt < 2; ++mt)
                acc[mt][nt] = __builtin_amdgcn_mfma_f32_16x16x32_bf16(afr[mt], bfr, acc[mt][nt], 0, 0, 0);
        }
        cur ^= 1;
    }

    float* Pp = P + (size_t)s * 15360;
    #pragma unroll
    for (int mt = 0; mt < 2; ++mt)
        #pragma unroll
        for (int nt = 0; nt < 8; ++nt)
            #pragma unroll
            for (int r = 0; r < 4; ++r) {
                int m = (wv * 2 + mt) * 16 + kb * 4 + r;
                int n = nt * 16 + lr;
                if (n < 120) Pp[m * 120 + n] = acc[mt][nt][r];
            }
}

// ---------------- tail v3 (r25-verbatim): 512 threads, 4-way split reduce + heads
__global__ __launch_bounds__(512) void tail_k(const float* __restrict__ P,
                                              const float* __restrict__ f1b,
                                              const float* __restrict__ f2w,
                                              const float* __restrict__ f2b,
                                              const float* __restrict__ f3w,
                                              const float* __restrict__ f3b,
                                              const float* __restrict__ qp,
                                              float* __restrict__ out) {
    __shared__ float red[4][120];
    __shared__ float x1[120];
    __shared__ float x2[84];
    int b = blockIdx.x, tid = threadIdx.x;
    if (tid < 480) {
        int part = tid / 120;
        int n = tid - part * 120;
        const float* p = P + (size_t)b * 120 + n;
        float acc = 0.0f;
        #pragma unroll 8
        for (int s = part; s < SPLITK; s += 4)
            acc += p[(size_t)s * 15360];
        red[part][n] = acc;
    }
    __syncthreads();
    if (tid < 120)
        x1[tid] = fmaxf((red[0][tid] + red[1][tid]) + (red[2][tid] + red[3][tid]) + f1b[tid], 0.0f);
    __syncthreads();
    if (tid < 84) {
        float acc = f2b[tid];
        const float* wr = f2w + tid * 120;
        #pragma unroll 4
        for (int n = 0; n < 120; ++n) acc = fmaf(x1[n], wr[n], acc);
        x2[tid] = fmaxf(acc, 0.0f);
    }
    __syncthreads();
    if (tid == 0) {
        float x = f3b[0];
        for (int m = 0; m < 84; ++m) x = fmaf(x2[m], f3w[m], x);
        float sr[16], si[16];
        #pragma unroll
        for (int i = 0; i < 16; ++i) { sr[i] = 0.0f; si[i] = 0.0f; }
        sr[0] = 1.0f;
        float c0 = cosf(0.5f * x), s0 = sinf(0.5f * x);
        #pragma unroll
        for (int w = 0; w < 4; ++w) {
            int mask = 8 >> w;
            #pragma unroll
            for (int idx = 0; idx < 16; ++idx) {
                if (idx & mask) continue;
                int i1 = idx | mask;
                float a0r = sr[idx], a0i = si[idx], a1r = sr[i1], a1i = si[i1];
                sr[idx] = c0 * a0r - s0 * a1r;  si[idx] = c0 * a0i - s0 * a1i;
                sr[i1]  = s0 * a0r + c0 * a1r;  si[i1]  = s0 * a0i + c0 * a1i;
            }
        }
        for (int layer = 0; layer < 2; ++layer) {
            #pragma unroll
            for (int w = 0; w < 4; ++w) {
                int gi = (layer * 4 + w) * 3;
                float phi = qp[gi], th = qp[gi + 1], om = qp[gi + 2];
                float hs = 0.5f * (phi + om), hd = 0.5f * (phi - om);
                float ct = cosf(0.5f * th), st = sinf(0.5f * th);
                float chs = cosf(hs), shs = sinf(hs);
                float chd = cosf(hd), shd = sinf(hd);
                float m00r = chs * ct,  m00i = -shs * ct;
                float m01r = -chd * st, m01i = -shd * st;
                float m10r = chd * st,  m10i = -shd * st;
                float m11r = chs * ct,  m11i = shs * ct;
                int mask = 8 >> w;
                #pragma unroll
                for (int idx = 0; idx < 16; ++idx) {
                    if (idx & mask) continue;
                    int i1 = idx | mask;
                    float a0r = sr[idx], a0i = si[idx], a1r = sr[i1], a1i = si[i1];
                    sr[idx] = m00r * a0r - m00i * a0i + m01r * a1r - m01i * a1i;
                    si[idx] = m00r * a0i + m00i * a0r + m01r * a1i + m01i * a1r;
                    sr[i1]  = m10r * a0r - m10i * a0i + m11r * a1r - m11i * a1i;
                    si[i1]  = m10r * a0i + m10i * a0r + m11r * a1i + m11i * a1r;
                }
            }
            #pragma unroll
            for (int cw = 0; cw < 3; ++cw) {
                int cm = 8 >> cw, tm = 8 >> (cw + 1);
                #pragma unroll
                for (int idx = 0; idx < 16; ++idx) {
                    if ((idx & cm) && !(idx & tm)) {
                        int i1 = idx | tm;
                        float tr = sr[idx]; sr[idx] = sr[i1]; sr[i1] = tr;
                        float ti = si[idx]; si[idx] = si[i1]; si[i1] = ti;
                    }
                }
            }
        }
        float q = 0.0f;
        #pragma unroll
        for (int idx = 0; idx < 16; ++idx) {
            float p2 = sr[idx] * sr[idx] + si[idx] * si[idx];
            q += (idx < 8) ? p2 : -p2;
        }
        float pr = 0.5f * (q + 1.0f);
        out[2 * b] = pr;
        out[2 * b + 1] = 1.0f - pr;
    }
}

extern "C" void kernel_launch(void* const* d_in, const int* in_sizes, int n_in,
                              void* d_out, int out_size, void* d_ws, size_t ws_size,
                              hipStream_t stream) {
    const float* inp = (const float*)d_in[0];
    const float* c1w = (const float*)d_in[1];
    const float* c1b = (const float*)d_in[2];
    const float* c2w = (const float*)d_in[3];
    const float* c2b = (const float*)d_in[4];
    const float* f1w = (const float*)d_in[5];
    const float* f1b = (const float*)d_in[6];
    const float* f2w = (const float*)d_in[7];
    const float* f2b = (const float*)d_in[8];
    const float* f3w = (const float*)d_in[9];
    const float* f3b = (const float*)d_in[10];
    const float* qp  = (const float*)d_in[11];
    float* out = (float*)d_out;
    float* ws = (float*)d_ws;

    // ws layout (float units):
    //   Bb (pool1 out, bf16)  @ 0          : 128*6*123*123 shorts = 5,809,536 f
    //   Db (pool2 out, bf16)  @ 5,809,536  : 128*KP shorts = 3,572,224 f
    //   P  (fc1 partials,f32) @ 9,381,760  : 256*128*120 = 3,932,160
    //   Wb (W1 bf16)          @ 13,313,920 : 120*KP shorts = 3,348,960 f
    unsigned short* Bb = (unsigned short*)ws;
    unsigned short* Db = (unsigned short*)(ws + 5809536);
    float* P = ws + 9381760;
    unsigned short* Wb = (unsigned short*)(ws + 13313920);

    wcvt_k<<<dim3(28, 120), 256, 0, stream>>>(f1w, Wb);
    conv1f_k<<<dim3(4, 4, 128), 256, 0, stream>>>(inp, c1w, c1b, Bb);
    conv2f_k<<<dim3(5, 5, 128), 256, 0, stream>>>(Bb, c2w, c2b, Db);
    fc1_k<<<dim3(SPLITK), 256, 0, stream>>>(Db, Wb, P);
    tail_k<<<128, 512, 0, stream>>>(P, f1b, f2w, f2b, f3w, f3b, qp, out);
}